// Round 9
// baseline (136.645 us; speedup 1.0000x reference)
//
#include <hip/hip_runtime.h>
#include <hip/hip_bf16.h>

#define BT 16      // B*T
#define NN 256     // nodes
#define DD 128     // feature dim
#define MROWS (BT*NN)   // 4096 total rows

typedef __bf16 bf16x8 __attribute__((ext_vector_type(8)));
typedef float  f32x4  __attribute__((ext_vector_type(4)));

#define LREL(z) ((z) >= 0.0f ? (z) : 0.2f * (z))

#define GRID_BLOCKS 512

// Monotonic single-use grid barrier.
// R7 lesson: ACQUIRE-per-poll -> buffer_inv storm, chip-wide cache thrash.
// R8 lesson: RELAXED plain-load poll -> stale XCD-local L2 line, barrier
//            resolves only on eviction (~60us each).
// Fix: poll with an atomic RMW (fetch_add 0). RMWs execute at the coherence
// point -- always see the live count -- with no invalidate side effects.
__device__ __forceinline__ void grid_barrier(unsigned* cnt) {
    __syncthreads();                 // all block threads done
    if (threadIdx.x == 0) {
        __threadfence();             // release: drain this block's stores
        __hip_atomic_fetch_add(cnt, 1u, __ATOMIC_RELAXED, __HIP_MEMORY_SCOPE_AGENT);
        while (__hip_atomic_fetch_add(cnt, 0u, __ATOMIC_RELAXED,
                                      __HIP_MEMORY_SCOPE_AGENT)
               < (unsigned)GRID_BLOCKS) {
            __builtin_amdgcn_s_sleep(4);
        }
        __threadfence();             // acquire side, once
    }
    __syncthreads();
}

// ============ Fused: prep -> barrier -> gemm -> barrier -> attn ============
// Bt layout (384x128 bf16 B^T):
//   rows [0,128)   : W^T        (h = x@W + bias)
//   rows [128,256) : (W@W1a)^T  (a = x@(W@W1a) + bias@W1a)
//   rows [256,384) : (W@W1b)^T  (b = x@(W@W1b) + bias@W1b + att_b1)
__global__ __launch_bounds__(256, 4) void fused_kernel(
        const float* __restrict__ x, const float* __restrict__ adj,
        const float* __restrict__ weight, const float* __restrict__ bias,
        const float* __restrict__ attw1, const float* __restrict__ attb1,
        const float* __restrict__ w2, const float* __restrict__ gamma,
        const float* __restrict__ beta, float* __restrict__ out,
        float* __restrict__ hbuf, float* __restrict__ abuf,
        float* __restrict__ bbuf, float* __restrict__ bias_full,
        __bf16* __restrict__ Bt, int* __restrict__ nbr,
        int* __restrict__ nbr_cnt, unsigned* __restrict__ bar) {
    int bid = blockIdx.x, tid = threadIdx.x;
    int w = tid >> 6, l = tid & 63;

    // ================= Phase 1: prep (blocks 0..64) =================
    if (bid < 32) {
        // combined weights via MFMA: 128 tiles of 16(n2) x 16(k), K=128
        int idx = bid * 4 + w;          // tile id 0..127
        int kt_t = idx & 7;             // k-tile
        int nt_t = idx >> 3;            // n2-tile
        int k0 = kt_t * 16, n0 = nt_t * 16;
        int lrow = l & 15, lk8 = (l >> 4) * 8;

        int n2 = n0 + lrow;
        int half = n2 >> 7, ncol = n2 & 127;

        bf16x8 Af[4];
#pragma unroll
        for (int kt = 0; kt < 4; ++kt) {
            const float* ap = attw1 + (size_t)(half * DD + lk8 + 32 * kt) * DD + ncol;
#pragma unroll
            for (int j = 0; j < 8; ++j)
                Af[kt][j] = (__bf16)ap[(size_t)j * DD];
        }
        const float* wrow = weight + (size_t)(k0 + lrow) * DD + lk8;
        bf16x8 Bf[4];
#pragma unroll
        for (int kt = 0; kt < 4; ++kt) {
            float4 u0 = *(const float4*)(wrow + 32 * kt);
            float4 u1 = *(const float4*)(wrow + 32 * kt + 4);
            Bf[kt][0]=(__bf16)u0.x; Bf[kt][1]=(__bf16)u0.y;
            Bf[kt][2]=(__bf16)u0.z; Bf[kt][3]=(__bf16)u0.w;
            Bf[kt][4]=(__bf16)u1.x; Bf[kt][5]=(__bf16)u1.y;
            Bf[kt][6]=(__bf16)u1.z; Bf[kt][7]=(__bf16)u1.w;
        }
        f32x4 acc = {0.f, 0.f, 0.f, 0.f};
        acc = __builtin_amdgcn_mfma_f32_16x16x32_bf16(Af[0], Bf[0], acc, 0, 0, 0);
        acc = __builtin_amdgcn_mfma_f32_16x16x32_bf16(Af[1], Bf[1], acc, 0, 0, 0);
        acc = __builtin_amdgcn_mfma_f32_16x16x32_bf16(Af[2], Bf[2], acc, 0, 0, 0);
        acc = __builtin_amdgcn_mfma_f32_16x16x32_bf16(Af[3], Bf[3], acc, 0, 0, 0);

        int kcol = k0 + lrow;
        int nrow = n0 + (l >> 4) * 4;
#pragma unroll
        for (int r = 0; r < 4; ++r)
            Bt[(size_t)(DD + nrow + r) * DD + kcol] = (__bf16)acc[r];
    } else if (bid < 48) {
        // Bt[n][k] = W[k][n] for n < 128
        int k0 = (bid - 32) * 8;
        int n = tid & 127, dk = tid >> 7;
        for (int p = 0; p < 4; ++p) {
            int k = k0 + p * 2 + dk;
            Bt[(size_t)n * DD + k] = (__bf16)weight[(size_t)k * DD + n];
        }
    } else if (bid < 64) {
        // neighbor-list compaction, one wave handles 4 rows
        for (int r = 0; r < 4; ++r) {
            int i = (bid - 48) * 16 + w * 4 + r;
            int cnt = 0;
            for (int jt = 0; jt < NN / 64; ++jt) {
                int j = jt * 64 + l;
                float v = adj[(size_t)i * NN + j];
                unsigned long long mask = __ballot(v != 0.f);
                if (v != 0.f) {
                    int pos = cnt + __popcll(mask & ((1ull << l) - 1ull));
                    nbr[i * NN + pos] = j;
                }
                cnt += __popcll(mask);
            }
            if (l == 0) nbr_cnt[i] = cnt;
        }
    } else if (bid == 64) {
        // bias_full[384]
        int half = tid >> 7, n = tid & 127;
        const float* w1col = attw1 + (size_t)(half * DD) * DD + n;
        float acc = 0.f;
#pragma unroll 8
        for (int k = 0; k < DD; ++k) acc += bias[k] * w1col[(size_t)k * DD];
        if (half) acc += attb1[n];
        bias_full[DD + tid] = acc;
        if (tid < DD) bias_full[tid] = bias[tid];
    }

    grid_barrier(bar + 0);

    // ====== Phase 2: gemm (512 blocks: 256 row-chunks x 2 n-halves) ========
    {
        int chunk = bid >> 1, parity = bid & 1;
        int row0 = chunk * 16;
        int lrow = l & 15, lk = (l >> 4) * 8;

        const float* abase = x + (size_t)(row0 + lrow) * DD + lk;
        bf16x8 af0, af1, af2, af3;
        {
            float4 u0, u1;
            u0 = *(const float4*)(abase +  0); u1 = *(const float4*)(abase +  4);
            af0[0]=(__bf16)u0.x; af0[1]=(__bf16)u0.y; af0[2]=(__bf16)u0.z; af0[3]=(__bf16)u0.w;
            af0[4]=(__bf16)u1.x; af0[5]=(__bf16)u1.y; af0[6]=(__bf16)u1.z; af0[7]=(__bf16)u1.w;
            u0 = *(const float4*)(abase + 32); u1 = *(const float4*)(abase + 36);
            af1[0]=(__bf16)u0.x; af1[1]=(__bf16)u0.y; af1[2]=(__bf16)u0.z; af1[3]=(__bf16)u0.w;
            af1[4]=(__bf16)u1.x; af1[5]=(__bf16)u1.y; af1[6]=(__bf16)u1.z; af1[7]=(__bf16)u1.w;
            u0 = *(const float4*)(abase + 64); u1 = *(const float4*)(abase + 68);
            af2[0]=(__bf16)u0.x; af2[1]=(__bf16)u0.y; af2[2]=(__bf16)u0.z; af2[3]=(__bf16)u0.w;
            af2[4]=(__bf16)u1.x; af2[5]=(__bf16)u1.y; af2[6]=(__bf16)u1.z; af2[7]=(__bf16)u1.w;
            u0 = *(const float4*)(abase + 96); u1 = *(const float4*)(abase + 100);
            af3[0]=(__bf16)u0.x; af3[1]=(__bf16)u0.y; af3[2]=(__bf16)u0.z; af3[3]=(__bf16)u0.w;
            af3[4]=(__bf16)u1.x; af3[5]=(__bf16)u1.y; af3[6]=(__bf16)u1.z; af3[7]=(__bf16)u1.w;
        }

#pragma unroll
        for (int t3 = 0; t3 < 3; ++t3) {
            int t = parity * 12 + 4 * t3 + w;
            int n0 = t * 16;
            const __bf16* bbase = Bt + (size_t)(n0 + lrow) * DD + lk;
            f32x4 acc = {0.f, 0.f, 0.f, 0.f};
            acc = __builtin_amdgcn_mfma_f32_16x16x32_bf16(af0, *(const bf16x8*)(bbase),      acc, 0, 0, 0);
            acc = __builtin_amdgcn_mfma_f32_16x16x32_bf16(af1, *(const bf16x8*)(bbase + 32), acc, 0, 0, 0);
            acc = __builtin_amdgcn_mfma_f32_16x16x32_bf16(af2, *(const bf16x8*)(bbase + 64), acc, 0, 0, 0);
            acc = __builtin_amdgcn_mfma_f32_16x16x32_bf16(af3, *(const bf16x8*)(bbase + 96), acc, 0, 0, 0);

            float bb = bias_full[n0 + lrow];
            float* dst = (t < 8) ? hbuf : (t < 16) ? abuf : bbuf;
            int nloc = (n0 & 127) + lrow;           // C/D: col = lane&15
            int rbase = row0 + (l >> 4) * 4;        //      row = (lane>>4)*4 + reg
            dst[(size_t)(rbase + 0) * DD + nloc] = acc[0] + bb;
            dst[(size_t)(rbase + 1) * DD + nloc] = acc[1] + bb;
            dst[(size_t)(rbase + 2) * DD + nloc] = acc[2] + bb;
            dst[(size_t)(rbase + 3) * DD + nloc] = acc[3] + bb;
        }
    }

    grid_barrier(bar + 16);

    // ====== Phase 3: attn + LN + ReLU (2048 waves x 2 bt each) =============
    {
        int wgl = bid * 4 + w;          // 0..2047
        int i   = wgl & 255;
        int bt0 = wgl >> 8;             // 0..7

        int cnt = nbr_cnt[i];
        int jreg = nbr[i * NN + l];     // lane l holds neighbor l's index
        float w20 = w2[l],  w21 = w2[l + 64];
        float gm0 = gamma[l], gm1 = gamma[l + 64];
        float bt_0 = beta[l], bt_1 = beta[l + 64];

#pragma unroll
        for (int rep = 0; rep < 2; ++rep) {
            int bt = bt0 + rep * 8;

            const float* arow = abuf + (size_t)(bt * NN + i) * DD;
            float a0 = arow[l], a1 = arow[l + 64];
            const float* bbase = bbuf + (size_t)bt * NN * DD;

            float m = -3.0e38f, myp = 0.f;
            int c = 0;
            for (; c + 3 < cnt; c += 4) {
                int j0 = __shfl(jreg, c);
                int j1 = __shfl(jreg, c + 1);
                int j2 = __shfl(jreg, c + 2);
                int j3 = __shfl(jreg, c + 3);
                const float* B0 = bbase + (size_t)j0 * DD;
                const float* B1 = bbase + (size_t)j1 * DD;
                const float* B2 = bbase + (size_t)j2 * DD;
                const float* B3 = bbase + (size_t)j3 * DD;
                float p0 = LREL(a0 + B0[l]) * w20 + LREL(a1 + B0[l + 64]) * w21;
                float p1 = LREL(a0 + B1[l]) * w20 + LREL(a1 + B1[l + 64]) * w21;
                float p2 = LREL(a0 + B2[l]) * w20 + LREL(a1 + B2[l + 64]) * w21;
                float p3 = LREL(a0 + B3[l]) * w20 + LREL(a1 + B3[l + 64]) * w21;
#pragma unroll
                for (int off = 32; off; off >>= 1) {
                    p0 += __shfl_xor(p0, off);
                    p1 += __shfl_xor(p1, off);
                    p2 += __shfl_xor(p2, off);
                    p3 += __shfl_xor(p3, off);
                }
                myp = (l == c)     ? p0 : myp;
                myp = (l == c + 1) ? p1 : myp;
                myp = (l == c + 2) ? p2 : myp;
                myp = (l == c + 3) ? p3 : myp;
                m = fmaxf(m, fmaxf(fmaxf(p0, p1), fmaxf(p2, p3)));
            }
            for (; c < cnt; ++c) {
                int j0 = __shfl(jreg, c);
                const float* B0 = bbase + (size_t)j0 * DD;
                float p0 = LREL(a0 + B0[l]) * w20 + LREL(a1 + B0[l + 64]) * w21;
#pragma unroll
                for (int off = 32; off; off >>= 1) p0 += __shfl_xor(p0, off);
                myp = (l == c) ? p0 : myp;
                m = fmaxf(m, p0);
            }

            float wgt = (l < cnt) ? expf(myp - m) : 0.f;
            float dsum = wgt;
#pragma unroll
            for (int off = 32; off; off >>= 1) dsum += __shfl_xor(dsum, off);
            float inv = 1.f / dsum;

            const float* hbase = hbuf + (size_t)bt * NN * DD;
            float acc0 = 0.f, acc1 = 0.f;
            c = 0;
            for (; c + 3 < cnt; c += 4) {
                float wc0 = __shfl(wgt, c),     wc1 = __shfl(wgt, c + 1);
                float wc2 = __shfl(wgt, c + 2), wc3 = __shfl(wgt, c + 3);
                int j0 = __shfl(jreg, c),     j1 = __shfl(jreg, c + 1);
                int j2 = __shfl(jreg, c + 2), j3 = __shfl(jreg, c + 3);
                const float* H0 = hbase + (size_t)j0 * DD;
                const float* H1 = hbase + (size_t)j1 * DD;
                const float* H2 = hbase + (size_t)j2 * DD;
                const float* H3 = hbase + (size_t)j3 * DD;
                acc0 += wc0 * H0[l]      + wc1 * H1[l]      + wc2 * H2[l]      + wc3 * H3[l];
                acc1 += wc0 * H0[l + 64] + wc1 * H1[l + 64] + wc2 * H2[l + 64] + wc3 * H3[l + 64];
            }
            for (; c < cnt; ++c) {
                float wc = __shfl(wgt, c);
                int j = __shfl(jreg, c);
                const float* H = hbase + (size_t)j * DD;
                acc0 += wc * H[l];
                acc1 += wc * H[l + 64];
            }

            const float* xrow = x + (size_t)(bt * NN + i) * DD;
            float y0 = acc0 * inv + xrow[l];
            float y1 = acc1 * inv + xrow[l + 64];

            float s = y0 + y1;
#pragma unroll
            for (int off = 32; off; off >>= 1) s += __shfl_xor(s, off);
            float mu = s * (1.0f / 128.0f);
            float v0 = y0 - mu, v1 = y1 - mu;
            float vs = v0 * v0 + v1 * v1;
#pragma unroll
            for (int off = 32; off; off >>= 1) vs += __shfl_xor(vs, off);
            float rstd = rsqrtf(vs * (1.0f / 128.0f) + 1e-5f);

            float o0 = v0 * rstd * gm0 + bt_0;
            float o1 = v1 * rstd * gm1 + bt_1;

            float* orow = out + (size_t)(bt * NN + i) * DD;
            orow[l]      = fmaxf(o0, 0.0f);
            orow[l + 64] = fmaxf(o1, 0.0f);
        }
    }
}

extern "C" void kernel_launch(void* const* d_in, const int* in_sizes, int n_in,
                              void* d_out, int out_size, void* d_ws, size_t ws_size,
                              hipStream_t stream) {
    const float* x      = (const float*)d_in[0];
    const float* adj    = (const float*)d_in[1];
    const float* weight = (const float*)d_in[2];
    const float* bias   = (const float*)d_in[3];
    const float* attw1  = (const float*)d_in[4];
    const float* attb1  = (const float*)d_in[5];
    const float* attw2  = (const float*)d_in[6];
    // d_in[7] = att_b2: uniform score shift -> cancels in softmax
    const float* gamma  = (const float*)d_in[8];
    const float* beta   = (const float*)d_in[9];
    float* out = (float*)d_out;

    char* p = (char*)d_ws;
    float* hbuf = (float*)p;          p += (size_t)MROWS * DD * 4;
    float* abuf = (float*)p;          p += (size_t)MROWS * DD * 4;
    float* bbuf = (float*)p;          p += (size_t)MROWS * DD * 4;
    float* bias_full = (float*)p;     p += 512 * 4;
    __bf16* Bt = (__bf16*)p;          p += (size_t)384 * DD * 2;
    int* nbr     = (int*)p;           p += (size_t)NN * NN * 4;
    int* nbr_cnt = (int*)p;           p += (size_t)NN * 4;
    unsigned* bar = (unsigned*)p;     // 2 counters (at +0 and +64B)

    hipMemsetAsync(bar, 0, 128, stream);

    fused_kernel<<<GRID_BLOCKS, 256, 0, stream>>>(
        x, adj, weight, bias, attw1, attb1, attw2, gamma, beta, out,
        hbuf, abuf, bbuf, bias_full, Bt, nbr, nbr_cnt, bar);
}

// Round 10
// 28.350 us; speedup vs baseline: 4.8200x; 4.8200x over previous
//
#include <hip/hip_runtime.h>
#include <hip/hip_bf16.h>

#define BT 16      // B*T
#define NN 256     // nodes
#define DD 128     // feature dim
#define MROWS (BT*NN)   // 4096 total rows

typedef __bf16 bf16x8 __attribute__((ext_vector_type(8)));
typedef float  f32x4  __attribute__((ext_vector_type(4)));

#define LREL(z) ((z) >= 0.0f ? (z) : 0.2f * (z))
#define HS_STRIDE 136   // bf16 elems per row: 272B, 16B-aligned rows

// ============ Kernel 1: two-stage GEMM, no prep dependency ================
// Per block (16 rows, 4 waves):
//   stage 1: h = x@W + bias          -> hbuf (global) + hs (LDS, bf16)
//   stage 2: a = h@W1a ; b = h@W1b + att_b1  (row-local in h!)
// B-fragments are strided fp32 loads from the raw weights (L2-hot),
// cast to bf16 in-register -- same pattern the R4/R5 prep Af used.
__global__ __launch_bounds__(256) void gemm2_kernel(
        const float* __restrict__ x, const float* __restrict__ weight,
        const float* __restrict__ bias, const float* __restrict__ attw1,
        const float* __restrict__ attb1,
        float* __restrict__ hbuf, float* __restrict__ abuf,
        float* __restrict__ bbuf) {
    int tid = threadIdx.x;
    int w = tid >> 6, l = tid & 63;
    int row0 = blockIdx.x * 16;
    int lrow = l & 15, lk8 = (l >> 4) * 8;

    __shared__ __align__(16) __bf16 hs[16][HS_STRIDE];

    // ---- A fragments from x: lane row (l&15), k = lk8 + 32*kt + j ----
    const float* abase = x + (size_t)(row0 + lrow) * DD + lk8;
    bf16x8 af[4];
#pragma unroll
    for (int kt = 0; kt < 4; ++kt) {
        float4 u0 = *(const float4*)(abase + 32 * kt);
        float4 u1 = *(const float4*)(abase + 32 * kt + 4);
        af[kt][0]=(__bf16)u0.x; af[kt][1]=(__bf16)u0.y;
        af[kt][2]=(__bf16)u0.z; af[kt][3]=(__bf16)u0.w;
        af[kt][4]=(__bf16)u1.x; af[kt][5]=(__bf16)u1.y;
        af[kt][6]=(__bf16)u1.z; af[kt][7]=(__bf16)u1.w;
    }

    // ---- stage 1: h tiles; wave w does n-tiles w and w+4 ----
#pragma unroll
    for (int s = 0; s < 2; ++s) {
        int n0 = (w + 4 * s) * 16;
        int ncol = n0 + lrow;
        // B-frag: lane col = ncol, elems k = lk8+32kt+j (strided fp32)
        bf16x8 wf[4];
#pragma unroll
        for (int kt = 0; kt < 4; ++kt) {
            const float* wp = weight + (size_t)(lk8 + 32 * kt) * DD + ncol;
#pragma unroll
            for (int j = 0; j < 8; ++j)
                wf[kt][j] = (__bf16)wp[(size_t)j * DD];
        }
        f32x4 acc = {0.f, 0.f, 0.f, 0.f};
        acc = __builtin_amdgcn_mfma_f32_16x16x32_bf16(af[0], wf[0], acc, 0, 0, 0);
        acc = __builtin_amdgcn_mfma_f32_16x16x32_bf16(af[1], wf[1], acc, 0, 0, 0);
        acc = __builtin_amdgcn_mfma_f32_16x16x32_bf16(af[2], wf[2], acc, 0, 0, 0);
        acc = __builtin_amdgcn_mfma_f32_16x16x32_bf16(af[3], wf[3], acc, 0, 0, 0);

        float bb = bias[ncol];
        int rloc = (l >> 4) * 4;               // D: row=(l>>4)*4+r, col=lane&15
        float* hout = hbuf + (size_t)(row0 + rloc) * DD + ncol;
#pragma unroll
        for (int r = 0; r < 4; ++r) {
            float hv = acc[r] + bb;
            hout[(size_t)r * DD] = hv;
            hs[rloc + r][ncol] = (__bf16)hv;
        }
    }
    __syncthreads();

    // ---- stage 2: a,b tiles from LDS h ----
    bf16x8 ha[4];
#pragma unroll
    for (int kt = 0; kt < 4; ++kt)
        ha[kt] = *(const bf16x8*)(&hs[lrow][lk8 + 32 * kt]);

#pragma unroll
    for (int h2 = 0; h2 < 2; ++h2) {
#pragma unroll
        for (int s = 0; s < 2; ++s) {
            int n0 = (w + 4 * s) * 16;
            int ncol = n0 + lrow;
            bf16x8 w1f[4];
#pragma unroll
            for (int kt = 0; kt < 4; ++kt) {
                const float* wp = attw1 + (size_t)(h2 * DD + lk8 + 32 * kt) * DD + ncol;
#pragma unroll
                for (int j = 0; j < 8; ++j)
                    w1f[kt][j] = (__bf16)wp[(size_t)j * DD];
            }
            f32x4 acc = {0.f, 0.f, 0.f, 0.f};
            acc = __builtin_amdgcn_mfma_f32_16x16x32_bf16(ha[0], w1f[0], acc, 0, 0, 0);
            acc = __builtin_amdgcn_mfma_f32_16x16x32_bf16(ha[1], w1f[1], acc, 0, 0, 0);
            acc = __builtin_amdgcn_mfma_f32_16x16x32_bf16(ha[2], w1f[2], acc, 0, 0, 0);
            acc = __builtin_amdgcn_mfma_f32_16x16x32_bf16(ha[3], w1f[3], acc, 0, 0, 0);

            float bb = h2 ? attb1[ncol] : 0.f;
            float* dst = (h2 ? bbuf : abuf) + (size_t)(row0 + (l >> 4) * 4) * DD + ncol;
#pragma unroll
            for (int r = 0; r < 4; ++r)
                dst[(size_t)r * DD] = acc[r] + bb;
        }
    }
}

// ============ Kernel 2: sparse attn + LN + ReLU (in-wave compaction) =======
// 4 waves/block, one (node, bt) per wave; lane l owns dims l and l+64.
// Adjacency compacted in-wave (R2-proven pattern) -- no prep dependency.
__global__ __launch_bounds__(256) void attn_kernel(
        const float* __restrict__ hbuf, const float* __restrict__ abuf,
        const float* __restrict__ bbuf, const float* __restrict__ x,
        const float* __restrict__ adj, const float* __restrict__ w2,
        const float* __restrict__ gamma, const float* __restrict__ beta,
        float* __restrict__ out) {
    int tid = threadIdx.x;
    int w = tid >> 6, l = tid & 63;
    int i  = (blockIdx.x & 63) * 4 + w;
    int bt = blockIdx.x >> 6;

    __shared__ int nbr_l[4][64];

    // ---- in-wave adjacency compaction (adj rows L2-hot) ----
    int cnt = 0;
    const float* adjrow = adj + (size_t)i * NN;
    for (int jt = 0; jt < NN / 64; ++jt) {
        int j = jt * 64 + l;
        float v = adjrow[j];
        unsigned long long mask = __ballot(v != 0.f);
        if (v != 0.f) {
            int pos = cnt + __popcll(mask & ((1ull << l) - 1ull));
            if (pos < 64) nbr_l[w][pos] = j;
        }
        cnt += __popcll(mask);
    }
    cnt = min(cnt, 64);
    int jreg = nbr_l[w][l];         // lane l holds neighbor l's index

    const float* arow = abuf + (size_t)(bt * NN + i) * DD;
    float a0 = arow[l], a1 = arow[l + 64];
    float w20 = w2[l],  w21 = w2[l + 64];
    const float* bbase = bbuf + (size_t)bt * NN * DD;

    // ---- scores: 4 neighbors/iter, 4 independent reduce chains ----
    float m = -3.0e38f, myp = 0.f;
    int c = 0;
    for (; c + 3 < cnt; c += 4) {
        int j0 = __shfl(jreg, c);
        int j1 = __shfl(jreg, c + 1);
        int j2 = __shfl(jreg, c + 2);
        int j3 = __shfl(jreg, c + 3);
        const float* B0 = bbase + (size_t)j0 * DD;
        const float* B1 = bbase + (size_t)j1 * DD;
        const float* B2 = bbase + (size_t)j2 * DD;
        const float* B3 = bbase + (size_t)j3 * DD;
        float p0 = LREL(a0 + B0[l]) * w20 + LREL(a1 + B0[l + 64]) * w21;
        float p1 = LREL(a0 + B1[l]) * w20 + LREL(a1 + B1[l + 64]) * w21;
        float p2 = LREL(a0 + B2[l]) * w20 + LREL(a1 + B2[l + 64]) * w21;
        float p3 = LREL(a0 + B3[l]) * w20 + LREL(a1 + B3[l + 64]) * w21;
#pragma unroll
        for (int off = 32; off; off >>= 1) {
            p0 += __shfl_xor(p0, off);
            p1 += __shfl_xor(p1, off);
            p2 += __shfl_xor(p2, off);
            p3 += __shfl_xor(p3, off);
        }
        myp = (l == c)     ? p0 : myp;
        myp = (l == c + 1) ? p1 : myp;
        myp = (l == c + 2) ? p2 : myp;
        myp = (l == c + 3) ? p3 : myp;
        m = fmaxf(m, fmaxf(fmaxf(p0, p1), fmaxf(p2, p3)));
    }
    for (; c < cnt; ++c) {
        int j0 = __shfl(jreg, c);
        const float* B0 = bbase + (size_t)j0 * DD;
        float p0 = LREL(a0 + B0[l]) * w20 + LREL(a1 + B0[l + 64]) * w21;
#pragma unroll
        for (int off = 32; off; off >>= 1) p0 += __shfl_xor(p0, off);
        myp = (l == c) ? p0 : myp;
        m = fmaxf(m, p0);
    }

    float wgt = (l < cnt) ? __expf(myp - m) : 0.f;
    float dsum = wgt;
#pragma unroll
    for (int off = 32; off; off >>= 1) dsum += __shfl_xor(dsum, off);
    float inv = 1.f / dsum;

    // ---- aggregate: 4 neighbors/iter ----
    const float* hbase = hbuf + (size_t)bt * NN * DD;
    float acc0 = 0.f, acc1 = 0.f;
    c = 0;
    for (; c + 3 < cnt; c += 4) {
        float wc0 = __shfl(wgt, c),     wc1 = __shfl(wgt, c + 1);
        float wc2 = __shfl(wgt, c + 2), wc3 = __shfl(wgt, c + 3);
        int j0 = __shfl(jreg, c),     j1 = __shfl(jreg, c + 1);
        int j2 = __shfl(jreg, c + 2), j3 = __shfl(jreg, c + 3);
        const float* H0 = hbase + (size_t)j0 * DD;
        const float* H1 = hbase + (size_t)j1 * DD;
        const float* H2 = hbase + (size_t)j2 * DD;
        const float* H3 = hbase + (size_t)j3 * DD;
        acc0 += wc0 * H0[l]      + wc1 * H1[l]      + wc2 * H2[l]      + wc3 * H3[l];
        acc1 += wc0 * H0[l + 64] + wc1 * H1[l + 64] + wc2 * H2[l + 64] + wc3 * H3[l + 64];
    }
    for (; c < cnt; ++c) {
        float wc = __shfl(wgt, c);
        int j = __shfl(jreg, c);
        const float* H = hbase + (size_t)j * DD;
        acc0 += wc * H[l];
        acc1 += wc * H[l + 64];
    }

    // ---- residual + LayerNorm + ReLU ----
    const float* xrow = x + (size_t)(bt * NN + i) * DD;
    float y0 = acc0 * inv + xrow[l];
    float y1 = acc1 * inv + xrow[l + 64];

    float s = y0 + y1;
#pragma unroll
    for (int off = 32; off; off >>= 1) s += __shfl_xor(s, off);
    float mu = s * (1.0f / 128.0f);
    float v0 = y0 - mu, v1 = y1 - mu;
    float vs = v0 * v0 + v1 * v1;
#pragma unroll
    for (int off = 32; off; off >>= 1) vs += __shfl_xor(vs, off);
    float rstd = rsqrtf(vs * (1.0f / 128.0f) + 1e-5f);

    float o0 = v0 * rstd * gamma[l]      + beta[l];
    float o1 = v1 * rstd * gamma[l + 64] + beta[l + 64];

    float* orow = out + (size_t)(bt * NN + i) * DD;
    orow[l]      = fmaxf(o0, 0.0f);
    orow[l + 64] = fmaxf(o1, 0.0f);
}

extern "C" void kernel_launch(void* const* d_in, const int* in_sizes, int n_in,
                              void* d_out, int out_size, void* d_ws, size_t ws_size,
                              hipStream_t stream) {
    const float* x      = (const float*)d_in[0];
    const float* adj    = (const float*)d_in[1];
    const float* weight = (const float*)d_in[2];
    const float* bias   = (const float*)d_in[3];
    const float* attw1  = (const float*)d_in[4];
    const float* attb1  = (const float*)d_in[5];
    const float* attw2  = (const float*)d_in[6];
    // d_in[7] = att_b2: uniform score shift -> cancels in softmax
    const float* gamma  = (const float*)d_in[8];
    const float* beta   = (const float*)d_in[9];
    float* out = (float*)d_out;

    char* p = (char*)d_ws;
    float* hbuf = (float*)p;          p += (size_t)MROWS * DD * 4;
    float* abuf = (float*)p;          p += (size_t)MROWS * DD * 4;
    float* bbuf = (float*)p;

    gemm2_kernel<<<MROWS / 16, 256, 0, stream>>>(x, weight, bias, attw1, attb1,
                                                 hbuf, abuf, bbuf);
    attn_kernel<<<NN / 4 * BT, 256, 0, stream>>>(hbuf, abuf, bbuf, x, adj,
                                                 attw2, gamma, beta, out);
}

// Round 11
// 26.968 us; speedup vs baseline: 5.0669x; 1.0512x over previous
//
#include <hip/hip_runtime.h>
#include <hip/hip_bf16.h>

#define BT 16      // B*T
#define NN 256     // nodes
#define DD 128     // feature dim
#define MROWS (BT*NN)   // 4096 total rows

typedef __bf16 bf16x8 __attribute__((ext_vector_type(8)));
typedef float  f32x4  __attribute__((ext_vector_type(4)));

#define LREL(z) ((z) >= 0.0f ? (z) : 0.2f * (z))
#define HS_STRIDE 136   // bf16 elems per row: 272B, 16B-aligned rows

// ============ Kernel 1: two-stage GEMM, parity-split stage 2 ==============
// 512 blocks x 256 thr (2 waves/SIMD). Block = (16-row chunk, parity).
//   stage 1 (all blocks): h = x@W + bias -> LDS (bf16); parity 0 also -> hbuf
//   stage 2: parity 0 -> a = h@W1a ; parity 1 -> b = h@W1b + att_b1
// Splitting stage 2 duplicates stage 1's FLOPs but doubles TLP and halves
// per-lane strided weight loads (192 -> 128) -- net win when latency-bound.
__global__ __launch_bounds__(256) void gemm2_kernel(
        const float* __restrict__ x, const float* __restrict__ weight,
        const float* __restrict__ bias, const float* __restrict__ attw1,
        const float* __restrict__ attb1,
        __bf16* __restrict__ hbuf, __bf16* __restrict__ abuf,
        __bf16* __restrict__ bbuf) {
    int tid = threadIdx.x;
    int w = tid >> 6, l = tid & 63;
    int chunk = blockIdx.x >> 1, parity = blockIdx.x & 1;
    int row0 = chunk * 16;
    int lrow = l & 15, lk8 = (l >> 4) * 8;

    __shared__ __align__(16) __bf16 hs[16][HS_STRIDE];

    // ---- A fragments from x: lane row (l&15), k = lk8 + 32*kt + j ----
    const float* abase = x + (size_t)(row0 + lrow) * DD + lk8;
    bf16x8 af[4];
#pragma unroll
    for (int kt = 0; kt < 4; ++kt) {
        float4 u0 = *(const float4*)(abase + 32 * kt);
        float4 u1 = *(const float4*)(abase + 32 * kt + 4);
        af[kt][0]=(__bf16)u0.x; af[kt][1]=(__bf16)u0.y;
        af[kt][2]=(__bf16)u0.z; af[kt][3]=(__bf16)u0.w;
        af[kt][4]=(__bf16)u1.x; af[kt][5]=(__bf16)u1.y;
        af[kt][6]=(__bf16)u1.z; af[kt][7]=(__bf16)u1.w;
    }

    // ---- stage 1: h tiles; wave w does n-tiles w and w+4 ----
#pragma unroll
    for (int s = 0; s < 2; ++s) {
        int n0 = (w + 4 * s) * 16;
        int ncol = n0 + lrow;
        bf16x8 wf[4];
#pragma unroll
        for (int kt = 0; kt < 4; ++kt) {
            const float* wp = weight + (size_t)(lk8 + 32 * kt) * DD + ncol;
#pragma unroll
            for (int j = 0; j < 8; ++j)
                wf[kt][j] = (__bf16)wp[(size_t)j * DD];
        }
        f32x4 acc = {0.f, 0.f, 0.f, 0.f};
        acc = __builtin_amdgcn_mfma_f32_16x16x32_bf16(af[0], wf[0], acc, 0, 0, 0);
        acc = __builtin_amdgcn_mfma_f32_16x16x32_bf16(af[1], wf[1], acc, 0, 0, 0);
        acc = __builtin_amdgcn_mfma_f32_16x16x32_bf16(af[2], wf[2], acc, 0, 0, 0);
        acc = __builtin_amdgcn_mfma_f32_16x16x32_bf16(af[3], wf[3], acc, 0, 0, 0);

        float bb = bias[ncol];
        int rloc = (l >> 4) * 4;               // D: row=(l>>4)*4+r, col=lane&15
        __bf16* hout = hbuf + (size_t)(row0 + rloc) * DD + ncol;
#pragma unroll
        for (int r = 0; r < 4; ++r) {
            __bf16 hv = (__bf16)(acc[r] + bb);
            hs[rloc + r][ncol] = hv;
            if (parity == 0) hout[(size_t)r * DD] = hv;
        }
    }
    __syncthreads();

    // ---- stage 2 (h2 = parity): a or b tiles from LDS h ----
    bf16x8 ha[4];
#pragma unroll
    for (int kt = 0; kt < 4; ++kt)
        ha[kt] = *(const bf16x8*)(&hs[lrow][lk8 + 32 * kt]);

#pragma unroll
    for (int s = 0; s < 2; ++s) {
        int n0 = (w + 4 * s) * 16;
        int ncol = n0 + lrow;
        bf16x8 w1f[4];
#pragma unroll
        for (int kt = 0; kt < 4; ++kt) {
            const float* wp = attw1 + (size_t)(parity * DD + lk8 + 32 * kt) * DD + ncol;
#pragma unroll
            for (int j = 0; j < 8; ++j)
                w1f[kt][j] = (__bf16)wp[(size_t)j * DD];
        }
        f32x4 acc = {0.f, 0.f, 0.f, 0.f};
        acc = __builtin_amdgcn_mfma_f32_16x16x32_bf16(ha[0], w1f[0], acc, 0, 0, 0);
        acc = __builtin_amdgcn_mfma_f32_16x16x32_bf16(ha[1], w1f[1], acc, 0, 0, 0);
        acc = __builtin_amdgcn_mfma_f32_16x16x32_bf16(ha[2], w1f[2], acc, 0, 0, 0);
        acc = __builtin_amdgcn_mfma_f32_16x16x32_bf16(ha[3], w1f[3], acc, 0, 0, 0);

        float bb = parity ? attb1[ncol] : 0.f;
        __bf16* dst = (parity ? bbuf : abuf) + (size_t)(row0 + (l >> 4) * 4) * DD + ncol;
#pragma unroll
        for (int r = 0; r < 4; ++r)
            dst[(size_t)r * DD] = (__bf16)(acc[r] + bb);
    }
}

// ============ Kernel 2: sparse attn + LN + ReLU (bf16 h/a/b) ==============
// 4 waves/block, one (node, bt) per wave; lane l owns dims l and l+64.
__global__ __launch_bounds__(256) void attn_kernel(
        const __bf16* __restrict__ hbuf, const __bf16* __restrict__ abuf,
        const __bf16* __restrict__ bbuf, const float* __restrict__ x,
        const float* __restrict__ adj, const float* __restrict__ w2,
        const float* __restrict__ gamma, const float* __restrict__ beta,
        float* __restrict__ out) {
    int tid = threadIdx.x;
    int w = tid >> 6, l = tid & 63;
    int i  = (blockIdx.x & 63) * 4 + w;
    int bt = blockIdx.x >> 6;

    __shared__ int nbr_l[4][64];

    // ---- in-wave adjacency compaction (adj rows L2-hot) ----
    int cnt = 0;
    const float* adjrow = adj + (size_t)i * NN;
    for (int jt = 0; jt < NN / 64; ++jt) {
        int j = jt * 64 + l;
        float v = adjrow[j];
        unsigned long long mask = __ballot(v != 0.f);
        if (v != 0.f) {
            int pos = cnt + __popcll(mask & ((1ull << l) - 1ull));
            if (pos < 64) nbr_l[w][pos] = j;
        }
        cnt += __popcll(mask);
    }
    cnt = min(cnt, 64);
    int jreg = nbr_l[w][l];         // lane l holds neighbor l's index

    const __bf16* arow = abuf + (size_t)(bt * NN + i) * DD;
    float a0 = (float)arow[l], a1 = (float)arow[l + 64];
    float w20 = w2[l],  w21 = w2[l + 64];
    const __bf16* bbase = bbuf + (size_t)bt * NN * DD;

    // ---- scores: 4 neighbors/iter, 4 independent reduce chains ----
    float m = -3.0e38f, myp = 0.f;
    int c = 0;
    for (; c + 3 < cnt; c += 4) {
        int j0 = __shfl(jreg, c);
        int j1 = __shfl(jreg, c + 1);
        int j2 = __shfl(jreg, c + 2);
        int j3 = __shfl(jreg, c + 3);
        const __bf16* B0 = bbase + (size_t)j0 * DD;
        const __bf16* B1 = bbase + (size_t)j1 * DD;
        const __bf16* B2 = bbase + (size_t)j2 * DD;
        const __bf16* B3 = bbase + (size_t)j3 * DD;
        float p0 = LREL(a0 + (float)B0[l]) * w20 + LREL(a1 + (float)B0[l + 64]) * w21;
        float p1 = LREL(a0 + (float)B1[l]) * w20 + LREL(a1 + (float)B1[l + 64]) * w21;
        float p2 = LREL(a0 + (float)B2[l]) * w20 + LREL(a1 + (float)B2[l + 64]) * w21;
        float p3 = LREL(a0 + (float)B3[l]) * w20 + LREL(a1 + (float)B3[l + 64]) * w21;
#pragma unroll
        for (int off = 32; off; off >>= 1) {
            p0 += __shfl_xor(p0, off);
            p1 += __shfl_xor(p1, off);
            p2 += __shfl_xor(p2, off);
            p3 += __shfl_xor(p3, off);
        }
        myp = (l == c)     ? p0 : myp;
        myp = (l == c + 1) ? p1 : myp;
        myp = (l == c + 2) ? p2 : myp;
        myp = (l == c + 3) ? p3 : myp;
        m = fmaxf(m, fmaxf(fmaxf(p0, p1), fmaxf(p2, p3)));
    }
    for (; c < cnt; ++c) {
        int j0 = __shfl(jreg, c);
        const __bf16* B0 = bbase + (size_t)j0 * DD;
        float p0 = LREL(a0 + (float)B0[l]) * w20 + LREL(a1 + (float)B0[l + 64]) * w21;
#pragma unroll
        for (int off = 32; off; off >>= 1) p0 += __shfl_xor(p0, off);
        myp = (l == c) ? p0 : myp;
        m = fmaxf(m, p0);
    }

    float wgt = (l < cnt) ? __expf(myp - m) : 0.f;
    float dsum = wgt;
#pragma unroll
    for (int off = 32; off; off >>= 1) dsum += __shfl_xor(dsum, off);
    float inv = 1.f / dsum;

    // ---- aggregate: 4 neighbors/iter ----
    const __bf16* hbase = hbuf + (size_t)bt * NN * DD;
    float acc0 = 0.f, acc1 = 0.f;
    c = 0;
    for (; c + 3 < cnt; c += 4) {
        float wc0 = __shfl(wgt, c),     wc1 = __shfl(wgt, c + 1);
        float wc2 = __shfl(wgt, c + 2), wc3 = __shfl(wgt, c + 3);
        int j0 = __shfl(jreg, c),     j1 = __shfl(jreg, c + 1);
        int j2 = __shfl(jreg, c + 2), j3 = __shfl(jreg, c + 3);
        const __bf16* H0 = hbase + (size_t)j0 * DD;
        const __bf16* H1 = hbase + (size_t)j1 * DD;
        const __bf16* H2 = hbase + (size_t)j2 * DD;
        const __bf16* H3 = hbase + (size_t)j3 * DD;
        acc0 += wc0 * (float)H0[l]      + wc1 * (float)H1[l]
              + wc2 * (float)H2[l]      + wc3 * (float)H3[l];
        acc1 += wc0 * (float)H0[l + 64] + wc1 * (float)H1[l + 64]
              + wc2 * (float)H2[l + 64] + wc3 * (float)H3[l + 64];
    }
    for (; c < cnt; ++c) {
        float wc = __shfl(wgt, c);
        int j = __shfl(jreg, c);
        const __bf16* H = hbase + (size_t)j * DD;
        acc0 += wc * (float)H[l];
        acc1 += wc * (float)H[l + 64];
    }

    // ---- residual + LayerNorm + ReLU ----
    const float* xrow = x + (size_t)(bt * NN + i) * DD;
    float y0 = acc0 * inv + xrow[l];
    float y1 = acc1 * inv + xrow[l + 64];

    float s = y0 + y1;
#pragma unroll
    for (int off = 32; off; off >>= 1) s += __shfl_xor(s, off);
    float mu = s * (1.0f / 128.0f);
    float v0 = y0 - mu, v1 = y1 - mu;
    float vs = v0 * v0 + v1 * v1;
#pragma unroll
    for (int off = 32; off; off >>= 1) vs += __shfl_xor(vs, off);
    float rstd = rsqrtf(vs * (1.0f / 128.0f) + 1e-5f);

    float o0 = v0 * rstd * gamma[l]      + beta[l];
    float o1 = v1 * rstd * gamma[l + 64] + beta[l + 64];

    float* orow = out + (size_t)(bt * NN + i) * DD;
    orow[l]      = fmaxf(o0, 0.0f);
    orow[l + 64] = fmaxf(o1, 0.0f);
}

extern "C" void kernel_launch(void* const* d_in, const int* in_sizes, int n_in,
                              void* d_out, int out_size, void* d_ws, size_t ws_size,
                              hipStream_t stream) {
    const float* x      = (const float*)d_in[0];
    const float* adj    = (const float*)d_in[1];
    const float* weight = (const float*)d_in[2];
    const float* bias   = (const float*)d_in[3];
    const float* attw1  = (const float*)d_in[4];
    const float* attb1  = (const float*)d_in[5];
    const float* attw2  = (const float*)d_in[6];
    // d_in[7] = att_b2: uniform score shift -> cancels in softmax
    const float* gamma  = (const float*)d_in[8];
    const float* beta   = (const float*)d_in[9];
    float* out = (float*)d_out;

    char* p = (char*)d_ws;
    __bf16* hbuf = (__bf16*)p;        p += (size_t)MROWS * DD * 2;
    __bf16* abuf = (__bf16*)p;        p += (size_t)MROWS * DD * 2;
    __bf16* bbuf = (__bf16*)p;

    gemm2_kernel<<<MROWS / 16 * 2, 256, 0, stream>>>(x, weight, bias, attw1, attb1,
                                                     hbuf, abuf, bbuf);
    attn_kernel<<<NN / 4 * BT, 256, 0, stream>>>(hbuf, abuf, bbuf, x, adj,
                                                 attw2, gamma, beta, out);
}